// Round 7
// baseline (187.881 us; speedup 1.0000x reference)
//
#include <hip/hip_runtime.h>

#define BT     16
#define NN     10242
#define CC     64
#define KK     9
#define NBR_   7
#define OO     64
#define MT     16            // rows (nodes) per tile
#define RS     584           // LDS itp row stride in bf16 (16B-aligned)
#define KT     18            // K tiles of 32
#define NTILES 641           // ceil(NN/MT)
#define TS     10            // tiles per block (sequential, pipelined)

using frag  = __attribute__((ext_vector_type(8))) short;   // 8 bf16 (4 VGPRs)
using f32x4 = __attribute__((ext_vector_type(4))) float;

static __device__ __forceinline__ unsigned short f2bf(float f) {
    union { float f; unsigned u; } v; v.f = f;
    unsigned r = v.u + 0x7fffu + ((v.u >> 16) & 1u);   // RNE
    return (unsigned short)(r >> 16);
}

// packed pair via v_cvt_pk_bf16_f32 (native RNE pack — bit-identical to f2bf).
// No builtin exists on gfx950; non-volatile asm stays scheduler-reorderable.
static __device__ __forceinline__ unsigned pk2(float a, float b) {
    unsigned r;
    asm("v_cvt_pk_bf16_f32 %0, %1, %2" : "=v"(r) : "v"(a), "v"(b));
    return r;
}

// q-permutation shared by producer and weight pack:
//   k in [0,8): q = (k>>2)*256 + c*4 + (k&3);  k==8: q = 512 + c
// wb[((t*4+ct)*64+lane)*8+j] = bf16(w[o][c][k]), q=t*32+(lane>>4)*8+j, o=ct*16+(lane&15)
__global__ void pack_w_kernel(const float* __restrict__ w, unsigned short* __restrict__ wb) {
    int i = blockIdx.x * blockDim.x + threadIdx.x;
    if (i >= KT * 4 * 64 * 8) return;
    int j  = i & 7;
    int l  = (i >> 3) & 63;
    int ct = (i >> 9) & 3;
    int t  = i >> 11;
    int q  = t * 32 + (l >> 4) * 8 + j;
    int o  = ct * 16 + (l & 15);
    int c, k;
    if (q < 512) { c = (q & 255) >> 2; k = (q >> 8) * 4 + (q & 3); }
    else         { c = q - 512;        k = 8; }
    wb[i] = f2bf(w[(o * CC + c) * KK + k]);
}

// Producer wave p: rows p*4..p*4+3 of one 16-node tile -> LDS buf. lane = channel.
static __device__ __forceinline__ void produce_tile(
    const float* __restrict__ xbt, const int* __restrict__ index,
    const float* __restrict__ m, unsigned short* __restrict__ buf,
    int n0, int p, int lane)
{
    int nu[4];
    #pragma unroll
    for (int r = 0; r < 4; ++r) {
        const int n = n0 + p * 4 + r;
        // clamp (reads stay in-bounds; junk rows never stored) + wave-uniform
        // so index/m go through scalar loads (K$/L2)
        nu[r] = __builtin_amdgcn_readfirstlane(n < NN ? n : (NN - 1));
    }
    float xv[4][NBR_];
    #pragma unroll
    for (int r = 0; r < 4; ++r) {
        const int* ip = index + nu[r] * NBR_;              // SGPR base -> s_load
        #pragma unroll
        for (int j = 0; j < NBR_; ++j)
            xv[r][j] = xbt[(size_t)ip[j] * CC + lane];     // coalesced 256B gather
    }
    #pragma unroll
    for (int r = 0; r < 4; ++r) {
        const int ns = p * 4 + r;
        const float* mp = m + nu[r] * (NBR_ * KK);         // SGPR base -> s_load
        float acc[KK];
        #pragma unroll
        for (int k = 0; k < KK; ++k) acc[k] = 0.f;
        #pragma unroll
        for (int j = 0; j < NBR_; ++j)
            #pragma unroll
            for (int k = 0; k < KK; ++k)
                acc[k] = fmaf(xv[r][j], mp[j * KK + k], acc[k]);

        uint2 q0, q1;
        q0.x = pk2(acc[0], acc[1]);
        q0.y = pk2(acc[2], acc[3]);
        q1.x = pk2(acc[4], acc[5]);
        q1.y = pk2(acc[6], acc[7]);
        unsigned short* row = &buf[ns * RS];
        *(uint2*)(&row[lane * 4])       = q0;              // 8B, 2-way banks = free
        *(uint2*)(&row[256 + lane * 4]) = q1;
        row[512 + lane] = f2bf(acc[8]);
    }
}

// Consumer wave ct: 16 nodes x 16 o-cols; B streamed from L2 (hot after tile 0).
static __device__ __forceinline__ void consume_tile(
    const unsigned short* __restrict__ buf, const frag* __restrict__ wbf,
    float* __restrict__ out, size_t obase, int n0, int ct, int lane, float bo)
{
    const int am   = lane & 15;
    const int half = lane >> 4;
    const int o    = ct * 16 + am;
    const unsigned short* arow = &buf[am * RS + half * 8];
    f32x4 acc = (f32x4){0.f, 0.f, 0.f, 0.f};
    #pragma unroll
    for (int t = 0; t < KT; ++t) {
        const frag a = *(const frag*)(arow + t * 32);       // ds_read_b128
        const frag b = wbf[(t * 4 + ct) * 64 + lane];       // L2-hot
        acc = __builtin_amdgcn_mfma_f32_16x16x32_bf16(a, b, acc, 0, 0, 0);
    }
    // D layout: col = lane&15, row = (lane>>4)*4 + i; all 4 consumer waves
    // store in the same interval -> full 256B out lines (no partial evicts)
    #pragma unroll
    for (int i = 0; i < 4; ++i) {
        const int n = n0 + half * 4 + i;
        if (n < NN) out[obase + (size_t)n * OO + o] = acc[i] + bo;
    }
}

__global__ __launch_bounds__(512, 8) void sphere_conv_kernel(
    const float* __restrict__ x,      // (BT, N, C)
    const int*   __restrict__ index,  // (N, NBR)
    const float* __restrict__ m,      // (N, NBR, K)
    const unsigned short* __restrict__ wb,  // packed B frags (bf16 bits)
    const float* __restrict__ bias,   // (O,)
    float*       __restrict__ out)    // (BT, N, O)
{
    __shared__ unsigned short itp_s[2][MT * RS];   // 2 x 18688B -> 4 blocks/CU

    const int tid    = threadIdx.x;
    const int w      = tid >> 6;                   // 0..7
    const int lane   = tid & 63;
    const int bt     = blockIdx.y;
    const int nt0    = blockIdx.x * TS;
    const int ntiles = (NTILES - nt0) < TS ? (NTILES - nt0) : TS;  // block-uniform

    const float* xbt   = x + (size_t)bt * NN * CC;
    const size_t obase = (size_t)bt * NN * OO;
    const frag*  wbf   = (const frag*)wb;

    const bool isprod = (w < 4);
    const int  role   = isprod ? w : (w - 4);      // producer p / consumer ct
    const float bo    = bias[(isprod ? 0 : role * 16) + (lane & 15)]; // consumers use it

    // Software pipeline: interval s has producers filling buf[s&1] with tile s
    // while consumers drain tile s-1 from buf[(s-1)&1]. One textual barrier.
    for (int s = 0; s <= ntiles; ++s) {
        if (isprod) {
            if (s < ntiles)
                produce_tile(xbt, index, m, itp_s[s & 1], (nt0 + s) * MT, role, lane);
        } else {
            if (s >= 1)
                consume_tile(itp_s[(s - 1) & 1], wbf, out, obase,
                             (nt0 + s - 1) * MT, role, lane, bo);
        }
        __syncthreads();
    }
}

extern "C" void kernel_launch(void* const* d_in, const int* in_sizes, int n_in,
                              void* d_out, int out_size, void* d_ws, size_t ws_size,
                              hipStream_t stream) {
    const float* x      = (const float*)d_in[0];
    const int*   index  = (const int*)  d_in[1];
    const float* m      = (const float*)d_in[2];
    const float* conv_w = (const float*)d_in[3];
    const float* conv_b = (const float*)d_in[4];
    float* out = (float*)d_out;
    unsigned short* wb = (unsigned short*)d_ws;   // 73728 B

    {   // pack weights into MFMA B-fragment order
        const int total = KT * 4 * 64 * 8;
        pack_w_kernel<<<(total + 255) / 256, 256, 0, stream>>>(conv_w, wb);
    }
    {   // producer/consumer pipelined blocks: 65 tile-runs x 16 bt
        dim3 grid((NTILES + TS - 1) / TS, BT);    // 65 x 16 = 1040 blocks
        sphere_conv_kernel<<<grid, 512, 0, stream>>>(x, index, m, wb, conv_b, out);
    }
}

// Round 8
// 163.302 us; speedup vs baseline: 1.1505x; 1.1505x over previous
//
#include <hip/hip_runtime.h>

#define BT    16
#define NN    10242
#define CC    64
#define KK    9
#define NBR_  7
#define OO    64
#define MT    16            // rows (nodes) per block
#define RS    584           // LDS itp row stride in bf16 (16B-aligned)
#define KT    18            // K tiles of 32
#define STG   7168          // per-wave x-stage bytes: 28 rows x 256B

using frag  = __attribute__((ext_vector_type(8))) short;   // 8 bf16 (4 VGPRs)
using f32x4 = __attribute__((ext_vector_type(4))) float;

static __device__ __forceinline__ unsigned short f2bf(float f) {
    union { float f; unsigned u; } v; v.f = f;
    unsigned r = v.u + 0x7fffu + ((v.u >> 16) & 1u);   // RNE
    return (unsigned short)(r >> 16);
}

// packed pair via v_cvt_pk_bf16_f32 (native RNE pack — bit-identical to f2bf)
static __device__ __forceinline__ unsigned pk2(float a, float b) {
    unsigned r;
    asm("v_cvt_pk_bf16_f32 %0, %1, %2" : "=v"(r) : "v"(a), "v"(b));
    return r;
}

// q-permutation shared by producer and weight pack:
//   k in [0,8): q = (k>>2)*256 + c*4 + (k&3);  k==8: q = 512 + c
// wb[((t*4+ct)*64+lane)*8+j] = bf16(w[o][c][k]), q=t*32+(lane>>4)*8+j, o=ct*16+(lane&15)
__global__ void pack_w_kernel(const float* __restrict__ w, unsigned short* __restrict__ wb) {
    int i = blockIdx.x * blockDim.x + threadIdx.x;
    if (i >= KT * 4 * 64 * 8) return;
    int j  = i & 7;
    int l  = (i >> 3) & 63;
    int ct = (i >> 9) & 3;
    int t  = i >> 11;
    int q  = t * 32 + (l >> 4) * 8 + j;
    int o  = ct * 16 + (l & 15);
    int c, k;
    if (q < 512) { c = (q & 255) >> 2; k = (q >> 8) * 4 + (q & 3); }
    else         { c = q - 512;        k = 8; }
    wb[i] = f2bf(w[(o * CC + c) * KK + k]);
}

__global__ __launch_bounds__(256, 5) void sphere_conv_kernel(
    const float* __restrict__ x,      // (BT, N, C)
    const int*   __restrict__ index,  // (N, NBR)
    const float* __restrict__ m,      // (N, NBR, K)
    const unsigned short* __restrict__ wb,  // packed B frags (bf16 bits)
    const float* __restrict__ bias,   // (O,)
    float*       __restrict__ out)    // (BT, N, O)
{
    // Time-shared LDS: phase 1 = x-stage (4 waves x 7168B = 28672B),
    // phase 2 = itp tile (18688B) overlaid on the same memory. Barrier between.
    __shared__ __align__(16) unsigned char smem[4 * STG];   // 28672B -> 5 blk/CU
    unsigned short* itp_s = (unsigned short*)smem;

    const int tid  = threadIdx.x;
    const int nt   = blockIdx.x;                // n-tile fastest (R6 layout)
    const int bt   = blockIdx.y;
    const int n0   = nt * MT;
    const int w    = tid >> 6;
    const int lane = tid & 63;
    const int sel  = lane >> 4;                 // which of 4 rows this lane stages
    const int lo16 = lane & 15;                 // 16B chunk within a 256B row

    // ---------------- Producer ----------------------------------------------
    // Stage ALL 28 neighbor rows (4 node-rows x 7 nbrs) via global_load_lds:
    // 7 instrs/wave, each lane loads 16B of one of 4 rows -> 1KB/instr, NO
    // VGPR destinations -> nothing for the compiler to serialize. One vmcnt.
    int nu[4];
    #pragma unroll
    for (int r = 0; r < 4; ++r) {
        const int n = n0 + w * 4 + r;
        // clamp (reads stay in-bounds; junk rows never stored) + wave-uniform
        // so index/m go through scalar loads (K$/L2)
        nu[r] = __builtin_amdgcn_readfirstlane(n < NN ? n : (NN - 1));
    }
    int ids[4 * NBR_];                          // wave-uniform -> SGPRs
    #pragma unroll
    for (int r = 0; r < 4; ++r) {
        const int* ip = index + nu[r] * NBR_;   // SGPR base -> s_load
        #pragma unroll
        for (int j = 0; j < NBR_; ++j) ids[r * NBR_ + j] = ip[j];
    }

    {
        const char* xb = (const char*)(x + (size_t)bt * NN * CC);
        #pragma unroll
        for (int i = 0; i < 7; ++i) {
            const int q = i * 4;                // rows q..q+3 of this wave's 28
            const int idj = sel == 0 ? ids[q]     : sel == 1 ? ids[q + 1]
                          : sel == 2 ? ids[q + 2] :            ids[q + 3];
            const void* src = xb + (size_t)idj * 256 + lo16 * 16;
            __builtin_amdgcn_global_load_lds(
                (const __attribute__((address_space(1))) void*)src,
                (__attribute__((address_space(3))) void*)(smem + w * STG + i * 1024),
                16, 0, 0);
        }
        asm volatile("s_waitcnt vmcnt(0)" ::: "memory");
    }

    // Interp from staged x (lane = channel; word = const + lane -> 2-way free)
    float acc[4][KK];
    #pragma unroll
    for (int r = 0; r < 4; ++r)
        #pragma unroll
        for (int k = 0; k < KK; ++k) acc[r][k] = 0.f;
    {
        const float* xs = (const float*)(smem + w * STG);
        #pragma unroll
        for (int r = 0; r < 4; ++r) {
            const float* mp = m + nu[r] * (NBR_ * KK);     // SGPR base -> s_load
            #pragma unroll
            for (int j = 0; j < NBR_; ++j) {
                const float xv = xs[(r * NBR_ + j) * 64 + lane];
                #pragma unroll
                for (int k = 0; k < KK; ++k)
                    acc[r][k] = fmaf(xv, mp[j * KK + k], acc[r][k]);
            }
        }
    }

    // Pack to bf16 in registers (20 regs live across the barrier)
    uint2 q0s[4], q1s[4];
    unsigned short h8[4];
    #pragma unroll
    for (int r = 0; r < 4; ++r) {
        q0s[r].x = pk2(acc[r][0], acc[r][1]);
        q0s[r].y = pk2(acc[r][2], acc[r][3]);
        q1s[r].x = pk2(acc[r][4], acc[r][5]);
        q1s[r].y = pk2(acc[r][6], acc[r][7]);
        h8[r]    = f2bf(acc[r][8]);
    }

    __syncthreads();    // all waves done READING stage before itp overwrites it

    #pragma unroll
    for (int r = 0; r < 4; ++r) {
        unsigned short* row = &itp_s[(w * 4 + r) * RS];
        *(uint2*)(&row[lane * 4])       = q0s[r];          // 8B, 2-way banks = free
        *(uint2*)(&row[256 + lane * 4]) = q1s[r];
        row[512 + lane] = h8[r];
    }

    __syncthreads();    // itp tile visible to all consumer waves

    // ------------- Consumer: wave = 16 rows x 16 cols (ct = wave id) --------
    const int ct   = w;
    const int am   = lane & 15;
    const int half = lane >> 4;

    f32x4 cacc = (f32x4){0.f, 0.f, 0.f, 0.f};

    const unsigned short* arow = &itp_s[am * RS + half * 8];
    const frag* wbf = (const frag*)wb;

    #pragma unroll
    for (int t = 0; t < KT; ++t) {
        const frag a = *(const frag*)(arow + t * 32);       // ds_read_b128
        const frag b = wbf[(t * 4 + ct) * 64 + lane];       // L2-hot
        cacc = __builtin_amdgcn_mfma_f32_16x16x32_bf16(a, b, cacc, 0, 0, 0);
    }

    // ---------------- Epilogue: bias + store ---------------------------------
    // D layout: col = lane&15, row = (lane>>4)*4 + i
    const size_t obase = (size_t)bt * NN * OO;
    {
        const int o  = ct * 16 + am;
        const float bo = bias[o];
        #pragma unroll
        for (int i = 0; i < 4; ++i) {
            const int n = n0 + half * 4 + i;
            if (n < NN) out[obase + (size_t)n * OO + o] = cacc[i] + bo;
        }
    }
}

extern "C" void kernel_launch(void* const* d_in, const int* in_sizes, int n_in,
                              void* d_out, int out_size, void* d_ws, size_t ws_size,
                              hipStream_t stream) {
    const float* x      = (const float*)d_in[0];
    const int*   index  = (const int*)  d_in[1];
    const float* m      = (const float*)d_in[2];
    const float* conv_w = (const float*)d_in[3];
    const float* conv_b = (const float*)d_in[4];
    float* out = (float*)d_out;
    unsigned short* wb = (unsigned short*)d_ws;   // 73728 B

    {   // pack weights into MFMA B-fragment order
        const int total = KT * 4 * 64 * 8;
        pack_w_kernel<<<(total + 255) / 256, 256, 0, stream>>>(conv_w, wb);
    }
    {   // fused gather + interp + MFMA conv (R6 grid: n-tile fastest)
        dim3 grid((NN + MT - 1) / MT, BT);        // 641 x 16
        sphere_conv_kernel<<<grid, 256, 0, stream>>>(x, index, m, wb, conv_b, out);
    }
}

// Round 9
// 144.803 us; speedup vs baseline: 1.2975x; 1.1278x over previous
//
#include <hip/hip_runtime.h>

#define BT    16
#define NN    10242
#define CC    64
#define KK    9
#define NBR_  7
#define OO    64
#define MT    16            // rows (nodes) per block  -> LDS 18.7KB -> 8 blocks/CU
#define RS    584           // LDS itp row stride in bf16 (16B-aligned)
#define KT    18            // K tiles of 32

using frag  = __attribute__((ext_vector_type(8))) short;   // 8 bf16 (4 VGPRs)
using f32x4 = __attribute__((ext_vector_type(4))) float;

static __device__ __forceinline__ unsigned short f2bf(float f) {
    union { float f; unsigned u; } v; v.f = f;
    unsigned r = v.u + 0x7fffu + ((v.u >> 16) & 1u);   // RNE
    return (unsigned short)(r >> 16);
}

// packed pair via v_cvt_pk_bf16_f32 (native RNE pack — bit-identical to f2bf)
static __device__ __forceinline__ unsigned pk2(float a, float b) {
    unsigned r;
    asm("v_cvt_pk_bf16_f32 %0, %1, %2" : "=v"(r) : "v"(a), "v"(b));
    return r;
}

// staged wait: hardware vmcnt wait + scheduler fence so dependent VALU cannot
// be hoisted above the wait (guide rule #18)
#define WAITV(n) do { asm volatile("s_waitcnt vmcnt(" #n ")" ::: "memory"); \
                      __builtin_amdgcn_sched_barrier(0); } while (0)

// q-permutation shared by producer and weight pack:
//   k in [0,8): q = (k>>2)*256 + c*4 + (k&3);  k==8: q = 512 + c
// wb[((t*4+ct)*64+lane)*8+j] = bf16(w[o][c][k]), q=t*32+(lane>>4)*8+j, o=ct*16+(lane&15)
__global__ void pack_w_kernel(const float* __restrict__ w, unsigned short* __restrict__ wb) {
    int i = blockIdx.x * blockDim.x + threadIdx.x;
    if (i >= KT * 4 * 64 * 8) return;
    int j  = i & 7;
    int l  = (i >> 3) & 63;
    int ct = (i >> 9) & 3;
    int t  = i >> 11;
    int q  = t * 32 + (l >> 4) * 8 + j;
    int o  = ct * 16 + (l & 15);
    int c, k;
    if (q < 512) { c = (q & 255) >> 2; k = (q >> 8) * 4 + (q & 3); }
    else         { c = q - 512;        k = 8; }
    wb[i] = f2bf(w[(o * CC + c) * KK + k]);
}

__global__ __launch_bounds__(256, 8) void sphere_conv_kernel(
    const float* __restrict__ x,      // (BT, N, C)
    const int*   __restrict__ index,  // (N, NBR)
    const float* __restrict__ m,      // (N, NBR, K)
    const unsigned short* __restrict__ wb,  // packed B frags (bf16 bits)
    const float* __restrict__ bias,   // (O,)
    float*       __restrict__ out)    // (BT, N, O)
{
    __shared__ unsigned short itp_s[MT * RS];   // 18688 B -> 8 blocks/CU

    const int tid  = threadIdx.x;
    const int nt   = blockIdx.x;                // n-tile fastest (R6 layout)
    const int bt   = blockIdx.y;
    const int n0   = nt * MT;
    const int w    = tid >> 6;
    const int lane = tid & 63;

    // ---------------- Producer: 4 rows/wave, lane = channel ------------------
    {
        const float* xbt = x + (size_t)bt * NN * CC;   // SGPR pair (saddr)

        int nu[4];
        #pragma unroll
        for (int r = 0; r < 4; ++r) {
            const int n = n0 + w * 4 + r;
            // clamp (reads stay in-bounds; junk rows never stored) + wave-uniform
            // so index/m go through scalar loads (K$/L2)
            nu[r] = __builtin_amdgcn_readfirstlane(n < NN ? n : (NN - 1));
        }
        int ids[4][NBR_];                       // wave-uniform -> SGPRs
        #pragma unroll
        for (int r = 0; r < 4; ++r) {
            const int* ip = index + nu[r] * NBR_;       // SGPR base -> s_load
            #pragma unroll
            for (int j = 0; j < NBR_; ++j) ids[r][j] = ip[j];
        }

        // FORCED-ILP gathers: 28 volatile loads, order pinned, all in flight.
        // Only vmcnt ops in this window (index/m are SMEM; B is behind the
        // barrier), so staged vmcnt counts below are exact.
        float xv[4][NBR_];
        const unsigned lb = (unsigned)(lane * 4);
        #pragma unroll
        for (int r = 0; r < 4; ++r)
            #pragma unroll
            for (int j = 0; j < NBR_; ++j) {
                const unsigned voff = (unsigned)ids[r][j] * 256u + lb;
                asm volatile("global_load_dword %0, %1, %2"
                             : "=v"(xv[r][j]) : "v"(voff), "s"(xbt));
            }

        #pragma unroll
        for (int r = 0; r < 4; ++r) {
            // wait only for this row's 7 loads; rows r+1.. stay in flight
            if (r == 0) WAITV(21);
            else if (r == 1) WAITV(14);
            else if (r == 2) WAITV(7);
            else WAITV(0);

            const float* mp = m + nu[r] * (NBR_ * KK);  // SGPR base -> s_load
            float acc[KK];
            #pragma unroll
            for (int k = 0; k < KK; ++k) acc[k] = 0.f;
            #pragma unroll
            for (int j = 0; j < NBR_; ++j)
                #pragma unroll
                for (int k = 0; k < KK; ++k)
                    acc[k] = fmaf(xv[r][j], mp[j * KK + k], acc[k]);

            uint2 q0, q1;
            q0.x = pk2(acc[0], acc[1]);
            q0.y = pk2(acc[2], acc[3]);
            q1.x = pk2(acc[4], acc[5]);
            q1.y = pk2(acc[6], acc[7]);
            unsigned short* row = &itp_s[(w * 4 + r) * RS];
            *(uint2*)(&row[lane * 4])       = q0;       // 8B, 2-way banks = free
            *(uint2*)(&row[256 + lane * 4]) = q1;
            row[512 + lane] = f2bf(acc[8]);
        }
    }
    __syncthreads();

    // ------------- Consumer: wave = 16 rows x 16 cols (ct = wave id) --------
    const int ct   = w;
    const int am   = lane & 15;
    const int half = lane >> 4;

    f32x4 cacc = (f32x4){0.f, 0.f, 0.f, 0.f};

    const unsigned short* arow = &itp_s[am * RS + half * 8];
    const frag* wbf = (const frag*)wb;

    #pragma unroll
    for (int t = 0; t < KT; ++t) {
        const frag a = *(const frag*)(arow + t * 32);       // ds_read_b128
        const frag b = wbf[(t * 4 + ct) * 64 + lane];       // L2-hot
        cacc = __builtin_amdgcn_mfma_f32_16x16x32_bf16(a, b, cacc, 0, 0, 0);
    }

    // ---------------- Epilogue: bias + store ---------------------------------
    // D layout: col = lane&15, row = (lane>>4)*4 + i
    const size_t obase = (size_t)bt * NN * OO;
    {
        const int o  = ct * 16 + am;
        const float bo = bias[o];
        #pragma unroll
        for (int i = 0; i < 4; ++i) {
            const int n = n0 + half * 4 + i;
            if (n < NN) out[obase + (size_t)n * OO + o] = cacc[i] + bo;
        }
    }
}

extern "C" void kernel_launch(void* const* d_in, const int* in_sizes, int n_in,
                              void* d_out, int out_size, void* d_ws, size_t ws_size,
                              hipStream_t stream) {
    const float* x      = (const float*)d_in[0];
    const int*   index  = (const int*)  d_in[1];
    const float* m      = (const float*)d_in[2];
    const float* conv_w = (const float*)d_in[3];
    const float* conv_b = (const float*)d_in[4];
    float* out = (float*)d_out;
    unsigned short* wb = (unsigned short*)d_ws;   // 73728 B

    {   // pack weights into MFMA B-fragment order
        const int total = KT * 4 * 64 * 8;
        pack_w_kernel<<<(total + 255) / 256, 256, 0, stream>>>(conv_w, wb);
    }
    {   // fused gather + interp + MFMA conv (R6 grid: n-tile fastest)
        dim3 grid((NN + MT - 1) / MT, BT);        // 641 x 16
        sphere_conv_kernel<<<grid, 256, 0, stream>>>(x, index, m, wb, conv_b, out);
    }
}